// Round 18
// baseline (40.893 us; speedup 1.0000x reference)
//
#include <hip/hip_runtime.h>

// IDST (DST-III, x2) via DIRECT N=4096-point complex FFT per 2 rows.
//   C_0 = x^A_{N-1} + j x^B_{N-1}
//   C_p = ê_p (z_{N-1-p} - j z_{p-1}),  ê_p = expk[p]
//   c = IDFT_N(C) (sign +); k even: y = (Re,Im) c_{k/2};
//   k odd: y = -(Re,Im) c_{(2N-1-k)/2}.
// R18 vs R17: (1) Y1/Y2 transpose planes interleaved float2 (b64) -> DS ops
// halved in S1w/S2r/S2w/S3r (all patterns at the balanced b64 bank floor);
// (2) final output emitted as paired float2 stores (thread j handles k=2j+512i
// and k+1 via c_{j+256i} / c_{4095-j-256i}) -> store count halved.

#define NN 4096

// In-place DFT-16, sign +1, natural order. Radix-4 x radix-4.
__device__ __forceinline__ void dft16(float (&re)[16], float (&im)[16]) {
    const float C1 = 0.92387953f, S1 = 0.38268343f;   // w16^1
    const float C2 = 0.70710678f;                     // w16^2 = (C2,C2)
    float Ar[16], Ai[16];                             // A[s0*4 + f0]
#pragma unroll
    for (int s0 = 0; s0 < 4; ++s0) {
        float ar = re[s0],      ai = im[s0];
        float br = re[s0 + 4],  bi = im[s0 + 4];
        float qr = re[s0 + 8],  qi = im[s0 + 8];
        float dr = re[s0 + 12], di = im[s0 + 12];
        float t0r = ar + qr, t0i = ai + qi;
        float t1r = ar - qr, t1i = ai - qi;
        float t2r = br + dr, t2i = bi + di;
        float t3r = br - dr, t3i = bi - di;
        Ar[s0*4+0] = t0r + t2r;  Ai[s0*4+0] = t0i + t2i;
        Ar[s0*4+1] = t1r - t3i;  Ai[s0*4+1] = t1i + t3r;   // +j t3
        Ar[s0*4+2] = t0r - t2r;  Ai[s0*4+2] = t0i - t2i;
        Ar[s0*4+3] = t1r + t3i;  Ai[s0*4+3] = t1i - t3r;   // -j t3
    }
#pragma unroll
    for (int f0 = 0; f0 < 4; ++f0) {
        float b0r = Ar[f0],      b0i = Ai[f0];
        float a1r = Ar[4 + f0],  a1i = Ai[4 + f0];
        float a2r = Ar[8 + f0],  a2i = Ai[8 + f0];
        float a3r = Ar[12 + f0], a3i = Ai[12 + f0];
        float b1r, b1i, b2r, b2i, b3r, b3i;
        if (f0 == 0) {
            b1r = a1r; b1i = a1i; b2r = a2r; b2i = a2i; b3r = a3r; b3i = a3i;
        } else if (f0 == 1) {
            b1r = a1r*C1 - a1i*S1;  b1i = a1r*S1 + a1i*C1;    // w^1
            b2r = (a2r - a2i)*C2;   b2i = (a2r + a2i)*C2;     // w^2
            b3r = a3r*S1 - a3i*C1;  b3i = a3r*C1 + a3i*S1;    // w^3
        } else if (f0 == 2) {
            b1r = (a1r - a1i)*C2;   b1i = (a1r + a1i)*C2;     // w^2
            b2r = -a2i;             b2i = a2r;                // w^4 = j
            b3r = -(a3r + a3i)*C2;  b3i = (a3r - a3i)*C2;     // w^6
        } else {
            b1r = a1r*S1 - a1i*C1;  b1i = a1r*C1 + a1i*S1;    // w^3
            b2r = -(a2r + a2i)*C2;  b2i = (a2r - a2i)*C2;     // w^6
            b3r = -a3r*C1 + a3i*S1; b3i = -a3r*S1 - a3i*C1;   // w^9
        }
        float t0r = b0r + b2r, t0i = b0i + b2i;
        float t1r = b0r - b2r, t1i = b0i - b2i;
        float t2r = b1r + b3r, t2i = b1i + b3i;
        float t3r = b1r - b3r, t3i = b1i - b3i;
        re[f0]      = t0r + t2r;  im[f0]      = t0i + t2i;
        re[f0 + 4]  = t1r - t3i;  im[f0 + 4]  = t1i + t3r;
        re[f0 + 8]  = t0r - t2r;  im[f0 + 8]  = t0i - t2i;
        re[f0 + 12] = t1r + t3i;  im[f0 + 12] = t1i - t3r;
    }
}

__global__ __launch_bounds__(256, 5) void idst_fft(const float* __restrict__ x,
                                                   const float2* __restrict__ expk,
                                                   float* __restrict__ y) {
    __shared__ float2 L2[4096];          // exactly 32 KB, interleaved

    const int j = threadIdx.x;
    const int blk = blockIdx.x;
    const float* xa = x + (size_t)(2 * blk) * NN;
    const float* xb = xa + NN;

    // ---- build C_p directly from global (p = j + 256 s) ----
    float cr[16], ci[16];
#pragma unroll
    for (int s = 0; s < 16; ++s) {
        const int p = j + 256 * s;
        const int pm1 = (p == 0) ? 0 : (p - 1);
        const float zar = xa[pm1],        zai = xb[pm1];        // z_{p-1}
        const float zbr = xa[NN - 1 - p], zbi = xb[NN - 1 - p]; // z_{N-1-p}
        const float2 e = expk[p];
        const float er = e.x, ei = -e.y;                       // ê_p
        const float wr = zbr + zai;                            // zb - j za
        const float wi = zbi - zar;
        float Cr = er * wr - ei * wi;
        float Ci = er * wi + ei * wr;
        if (p == 0) { Cr = zbr; Ci = zbi; }                    // C_0
        cr[s] = Cr; ci[s] = Ci;
    }

    // ---- S1: DFT-16 over s -> f; twiddle e^{j2pi j f/4096}; write Y1 ----
    dft16(cr, ci);
    {
        float sn, cs;
        __sincosf((float)j * 1.5339807879e-3f, &sn, &cs);   // 2pi/4096
        float tr = 1.f, ti = 0.f;
#pragma unroll
        for (int f = 0; f < 16; ++f) {
            L2[f * 256 + ((j + 2 * f) & 255)] =             // rotation swizzle
                make_float2(cr[f] * tr - ci[f] * ti,
                            cr[f] * ti + ci[f] * tr);
            float nr = tr * cs - ti * sn;
            ti = tr * sn + ti * cs;
            tr = nr;
        }
    }
    __syncthreads();

    // ---- S2: (f, jA) = (j&15, j>>4); DFT-16 over jB; twiddle; write Y2 ----
    const int f = j & 15;
    const int jA = j >> 4;
#pragma unroll
    for (int jB = 0; jB < 16; ++jB) {
        float2 v = L2[f * 256 + ((jA + 16 * jB + 2 * f) & 255)];
        cr[jB] = v.x;
        ci[jB] = v.y;
    }
    dft16(cr, ci);
    __syncthreads();      // Y1 reads complete before overwrite
    {
        float sn, cs;
        __sincosf((float)jA * 2.4543692606e-2f, &sn, &cs);  // 2pi/256
        float tr = 1.f, ti = 0.f;
#pragma unroll
        for (int g0 = 0; g0 < 16; ++g0) {
            L2[((f + 16 * g0 + 8 * jA) & 255) + 256 * jA] =
                make_float2(cr[g0] * tr - ci[g0] * ti,
                            cr[g0] * ti + ci[g0] * tr);
            float nr = tr * cs - ti * sn;
            ti = tr * sn + ti * cs;
            tr = nr;
        }
    }
    __syncthreads();

    // ---- S3: (f, g0) = (j&15, j>>4); DFT-16 over jA' -> g1; write c[q] ----
#pragma unroll
    for (int t = 0; t < 16; ++t) {
        float2 v = L2[((f + 16 * (j >> 4) + 8 * t) & 255) + 256 * t];
        cr[t] = v.x;
        ci[t] = v.y;
    }
    dft16(cr, ci);
    __syncthreads();      // Y2 reads complete
#pragma unroll
    for (int g1 = 0; g1 < 16; ++g1) {
        L2[j + 256 * g1] = make_float2(cr[g1], ci[g1]);   // q = j + 256 g1
    }
    __syncthreads();

    // ---- final: paired read-off, float2 stores ----
    // thread j, i: k = 2j + 512i (even) uses c_{j+256i}; k+1 uses c_{4095-j-256i}
    float* ya = y + (size_t)(2 * blk) * NN;
    float* yb = ya + NN;
#pragma unroll
    for (int i = 0; i < 8; ++i) {
        const int k0 = 2 * j + 512 * i;
        const float2 ve = L2[j + 256 * i];            // even output
        const float2 vo = L2[4095 - j - 256 * i];     // odd output (negated)
        *(float2*)(ya + k0) = make_float2(ve.x, -vo.x);
        *(float2*)(yb + k0) = make_float2(ve.y, -vo.y);
    }
}

extern "C" void kernel_launch(void* const* d_in, const int* in_sizes, int n_in,
                              void* d_out, int out_size, void* d_ws, size_t ws_size,
                              hipStream_t stream) {
    const float*  x    = (const float*)d_in[0];
    const float2* expk = (const float2*)d_in[1];
    float* out = (float*)d_out;

    idst_fft<<<NN / 2, 256, 0, stream>>>(x, expk, out);
}

// Round 19
// 29.603 us; speedup vs baseline: 1.3814x; 1.3814x over previous
//
#include <hip/hip_runtime.h>

// IDST (DST-III, x2) via DIRECT N=4096-point complex FFT per 2 rows.
//   C_0 = x^A_{N-1} + j x^B_{N-1}
//   C_p = ê_p (z_{N-1-p} - j z_{p-1}),  ê_p = expk[p]
//   c = IDFT_N(C) (sign +); k even: y = (Re,Im) c_{k/2};
//   k odd: y = -(Re,Im) c_{(2N-1-k)/2}.
// R19 = exact revert to R17 (29.6 us, proven stable). R18's b64-LDS +
// paired-store variant spilled (b64 ops need even-aligned reg pairs ->
// pressure past the (256,5)=102-VGPR cliff; WRITE +24MB scratch, 41 us).
// This kernel is at the stable register/occupancy optimum of the design:
// scalar b32 LDS planes, 5 blocks/CU, 32 KB plane, zero conflicts.

#define NN 4096

// In-place DFT-16, sign +1, natural order. Radix-4 x radix-4.
__device__ __forceinline__ void dft16(float (&re)[16], float (&im)[16]) {
    const float C1 = 0.92387953f, S1 = 0.38268343f;   // w16^1
    const float C2 = 0.70710678f;                     // w16^2 = (C2,C2)
    float Ar[16], Ai[16];                             // A[s0*4 + f0]
#pragma unroll
    for (int s0 = 0; s0 < 4; ++s0) {
        float ar = re[s0],      ai = im[s0];
        float br = re[s0 + 4],  bi = im[s0 + 4];
        float qr = re[s0 + 8],  qi = im[s0 + 8];
        float dr = re[s0 + 12], di = im[s0 + 12];
        float t0r = ar + qr, t0i = ai + qi;
        float t1r = ar - qr, t1i = ai - qi;
        float t2r = br + dr, t2i = bi + di;
        float t3r = br - dr, t3i = bi - di;
        Ar[s0*4+0] = t0r + t2r;  Ai[s0*4+0] = t0i + t2i;
        Ar[s0*4+1] = t1r - t3i;  Ai[s0*4+1] = t1i + t3r;   // +j t3
        Ar[s0*4+2] = t0r - t2r;  Ai[s0*4+2] = t0i - t2i;
        Ar[s0*4+3] = t1r + t3i;  Ai[s0*4+3] = t1i - t3r;   // -j t3
    }
#pragma unroll
    for (int f0 = 0; f0 < 4; ++f0) {
        float b0r = Ar[f0],      b0i = Ai[f0];
        float a1r = Ar[4 + f0],  a1i = Ai[4 + f0];
        float a2r = Ar[8 + f0],  a2i = Ai[8 + f0];
        float a3r = Ar[12 + f0], a3i = Ai[12 + f0];
        float b1r, b1i, b2r, b2i, b3r, b3i;
        if (f0 == 0) {
            b1r = a1r; b1i = a1i; b2r = a2r; b2i = a2i; b3r = a3r; b3i = a3i;
        } else if (f0 == 1) {
            b1r = a1r*C1 - a1i*S1;  b1i = a1r*S1 + a1i*C1;    // w^1
            b2r = (a2r - a2i)*C2;   b2i = (a2r + a2i)*C2;     // w^2
            b3r = a3r*S1 - a3i*C1;  b3i = a3r*C1 + a3i*S1;    // w^3
        } else if (f0 == 2) {
            b1r = (a1r - a1i)*C2;   b1i = (a1r + a1i)*C2;     // w^2
            b2r = -a2i;             b2i = a2r;                // w^4 = j
            b3r = -(a3r + a3i)*C2;  b3i = (a3r - a3i)*C2;     // w^6
        } else {
            b1r = a1r*S1 - a1i*C1;  b1i = a1r*C1 + a1i*S1;    // w^3
            b2r = -(a2r + a2i)*C2;  b2i = (a2r - a2i)*C2;     // w^6
            b3r = -a3r*C1 + a3i*S1; b3i = -a3r*S1 - a3i*C1;   // w^9
        }
        float t0r = b0r + b2r, t0i = b0i + b2i;
        float t1r = b0r - b2r, t1i = b0i - b2i;
        float t2r = b1r + b3r, t2i = b1i + b3i;
        float t3r = b1r - b3r, t3i = b1i - b3i;
        re[f0]      = t0r + t2r;  im[f0]      = t0i + t2i;
        re[f0 + 4]  = t1r - t3i;  im[f0 + 4]  = t1i + t3r;
        re[f0 + 8]  = t0r - t2r;  im[f0 + 8]  = t0i - t2i;
        re[f0 + 12] = t1r + t3i;  im[f0 + 12] = t1i - t3r;
    }
}

__global__ __launch_bounds__(256, 5) void idst_fft(const float* __restrict__ x,
                                                   const float2* __restrict__ expk,
                                                   float* __restrict__ y) {
    __shared__ float L[8192];            // exactly 32 KB
    float2* const L2 = (float2*)L;

    const int j = threadIdx.x;
    const int blk = blockIdx.x;
    const float* xa = x + (size_t)(2 * blk) * NN;
    const float* xb = xa + NN;

    // ---- build C_p directly from global (p = j + 256 s) ----
    float cr[16], ci[16];
#pragma unroll
    for (int s = 0; s < 16; ++s) {
        const int p = j + 256 * s;
        const int pm1 = (p == 0) ? 0 : (p - 1);
        const float zar = xa[pm1],        zai = xb[pm1];        // z_{p-1}
        const float zbr = xa[NN - 1 - p], zbi = xb[NN - 1 - p]; // z_{N-1-p}
        const float2 e = expk[p];
        const float er = e.x, ei = -e.y;                       // ê_p
        const float wr = zbr + zai;                            // zb - j za
        const float wi = zbi - zar;
        float Cr = er * wr - ei * wi;
        float Ci = er * wi + ei * wr;
        if (p == 0) { Cr = zbr; Ci = zbi; }                    // C_0
        cr[s] = Cr; ci[s] = Ci;
    }

    // ---- S1: DFT-16 over s -> f; twiddle e^{j2pi j f/4096}; write Y1 ----
    dft16(cr, ci);
    {
        float sn, cs;
        __sincosf((float)j * 1.5339807879e-3f, &sn, &cs);   // 2pi/4096
        float tr = 1.f, ti = 0.f;
#pragma unroll
        for (int f = 0; f < 16; ++f) {
            int a = f * 256 + ((j + 2 * f) & 255);          // rotation swizzle
            L[a]        = cr[f] * tr - ci[f] * ti;
            L[4096 + a] = cr[f] * ti + ci[f] * tr;
            float nr = tr * cs - ti * sn;
            ti = tr * sn + ti * cs;
            tr = nr;
        }
    }
    __syncthreads();

    // ---- S2: (f, jA) = (j&15, j>>4); DFT-16 over jB; twiddle; write Y2 ----
    const int f = j & 15;
    const int jA = j >> 4;
#pragma unroll
    for (int jB = 0; jB < 16; ++jB) {
        int a = f * 256 + ((jA + 16 * jB + 2 * f) & 255);
        cr[jB] = L[a];
        ci[jB] = L[4096 + a];
    }
    dft16(cr, ci);
    __syncthreads();      // Y1 reads complete before overwrite
    {
        float sn, cs;
        __sincosf((float)jA * 2.4543692606e-2f, &sn, &cs);  // 2pi/256
        float tr = 1.f, ti = 0.f;
#pragma unroll
        for (int g0 = 0; g0 < 16; ++g0) {
            int a = ((f + 16 * g0 + 8 * jA) & 255) + 256 * jA;
            L[a]        = cr[g0] * tr - ci[g0] * ti;
            L[4096 + a] = cr[g0] * ti + ci[g0] * tr;
            float nr = tr * cs - ti * sn;
            ti = tr * sn + ti * cs;
            tr = nr;
        }
    }
    __syncthreads();

    // ---- S3: (f, g0) = (j&15, j>>4); DFT-16 over jA' -> g1; write c[q] ----
#pragma unroll
    for (int t = 0; t < 16; ++t) {
        int a = ((f + 16 * (j >> 4) + 8 * t) & 255) + 256 * t;
        cr[t] = L[a];
        ci[t] = L[4096 + a];
    }
    dft16(cr, ci);
    __syncthreads();      // Y2 reads complete
#pragma unroll
    for (int g1 = 0; g1 < 16; ++g1) {
        L2[j + 256 * g1] = make_float2(cr[g1], ci[g1]);   // q = j + 256 g1
    }
    __syncthreads();

    // ---- final: output read-off ----
    float* ya = y + (size_t)(2 * blk) * NN;
    float* yb = ya + NN;
#pragma unroll
    for (int i = 0; i < 16; ++i) {
        int k = j + 256 * i;
        int q;
        float sg;
        if (k & 1) { q = (2 * NN - 1 - k) >> 1; sg = -1.0f; }
        else       { q = k >> 1;                sg = 1.0f; }
        float2 v = L2[q];
        ya[k] = sg * v.x;
        yb[k] = sg * v.y;
    }
}

extern "C" void kernel_launch(void* const* d_in, const int* in_sizes, int n_in,
                              void* d_out, int out_size, void* d_ws, size_t ws_size,
                              hipStream_t stream) {
    const float*  x    = (const float*)d_in[0];
    const float2* expk = (const float2*)d_in[1];
    float* out = (float*)d_out;

    idst_fft<<<NN / 2, 256, 0, stream>>>(x, expk, out);
}